// Round 1
// baseline (340.922 us; speedup 1.0000x reference)
//
#include <hip/hip_runtime.h>
#include <hip/hip_bf16.h>

// Problem constants (fixed by the reference)
constexpr int BATCH  = 32;
constexpr int TIME   = 1024;
constexpr int IN_DIM = 512;
constexpr int HIDDEN = 512;

constexpr int GM = BATCH * TIME;   // 32768  (GEMM M)
constexpr int GN = HIDDEN;         // 512    (GEMM N)
constexpr int GK = IN_DIM;         // 512    (GEMM K)

// ---------------- Phase 1: fp32 SGEMM with bias ----------------
// C[m,n] = sum_k A[m,k]*B[k,n] ; then +bias[n]  (separate add, matches numpy)
// Tile: 128x128x16, 256 threads, 8x8 microtile per thread.
constexpr int BM = 128;
constexpr int BN = 128;
constexpr int BK = 16;
constexpr int LDAs = BM + 4;   // padded leading dims (floats)
constexpr int LDBs = BN + 4;

__global__ __launch_bounds__(256) void sgemm_bias_kernel(
    const float* __restrict__ A,     // [GM, GK]
    const float* __restrict__ B,     // [GK, GN]
    const float* __restrict__ bias,  // [GN]
    float* __restrict__ C)           // [GM, GN]
{
    __shared__ __align__(16) float As[BK * LDAs];
    __shared__ __align__(16) float Bs[BK * LDBs];

    const int tid = threadIdx.x;           // 0..255
    const int bm  = blockIdx.y * BM;
    const int bn  = blockIdx.x * BN;

    // wave-quadrant mapping: wave w covers a 64x64 quadrant; within the wave
    // lanes form an 8x8 grid -> LDS frag reads are 2-way aliased (free).
    const int w    = tid >> 6;
    const int lane = tid & 63;
    const int row0 = (w >> 1) * 64 + (lane >> 3) * 8;   // 0..120 within tile
    const int col0 = (w & 1)  * 64 + (lane & 7)  * 8;

    float acc[8][8];
    #pragma unroll
    for (int i = 0; i < 8; ++i)
        #pragma unroll
        for (int j = 0; j < 8; ++j) acc[i][j] = 0.0f;

    for (int k0 = 0; k0 < GK; k0 += BK) {
        // ---- global loads to registers (overlap with previous compute) ----
        float4 va[2], vb[2];
        #pragma unroll
        for (int i = 0; i < 2; ++i) {
            const int q  = tid + i * 256;
            // A tile quad: row q>>2 (0..127), col (q&3)*4 (0..12)
            const int ar = q >> 2;
            const int ac = (q & 3) << 2;
            va[i] = *reinterpret_cast<const float4*>(
                A + (size_t)(bm + ar) * GK + k0 + ac);
            // B tile quad: row q>>5 (0..15), col (q&31)*4 (0..124)
            const int br = q >> 5;
            const int bc = (q & 31) << 2;
            vb[i] = *reinterpret_cast<const float4*>(
                B + (size_t)(k0 + br) * GN + bn + bc);
        }

        __syncthreads();   // previous tile's compute done before overwrite

        #pragma unroll
        for (int i = 0; i < 2; ++i) {
            const int q  = tid + i * 256;
            const int ar = q >> 2;
            const int ac = (q & 3) << 2;
            // store A transposed: As[k][m]
            As[(ac + 0) * LDAs + ar] = va[i].x;
            As[(ac + 1) * LDAs + ar] = va[i].y;
            As[(ac + 2) * LDAs + ar] = va[i].z;
            As[(ac + 3) * LDAs + ar] = va[i].w;
            const int br = q >> 5;
            const int bc = (q & 31) << 2;
            *reinterpret_cast<float4*>(&Bs[br * LDBs + bc]) = vb[i];
        }

        __syncthreads();

        // ---- compute 16 k-steps ----
        #pragma unroll
        for (int kk = 0; kk < BK; ++kk) {
            const float4 a0 = *reinterpret_cast<const float4*>(&As[kk * LDAs + row0]);
            const float4 a1 = *reinterpret_cast<const float4*>(&As[kk * LDAs + row0 + 4]);
            const float4 b0 = *reinterpret_cast<const float4*>(&Bs[kk * LDBs + col0]);
            const float4 b1 = *reinterpret_cast<const float4*>(&Bs[kk * LDBs + col0 + 4]);
            const float ar[8] = {a0.x, a0.y, a0.z, a0.w, a1.x, a1.y, a1.z, a1.w};
            const float br[8] = {b0.x, b0.y, b0.z, b0.w, b1.x, b1.y, b1.z, b1.w};
            #pragma unroll
            for (int i = 0; i < 8; ++i)
                #pragma unroll
                for (int j = 0; j < 8; ++j)
                    acc[i][j] = fmaf(ar[i], br[j], acc[i][j]);
        }
    }

    // ---- epilogue: add bias (separate fp32 add, like numpy), store ----
    #pragma unroll
    for (int i = 0; i < 8; ++i) {
        const size_t r = (size_t)(bm + row0 + i);
        #pragma unroll
        for (int j = 0; j < 8; j += 4) {
            float4 v;
            v.x = __fadd_rn(acc[i][j + 0], bias[bn + col0 + j + 0]);
            v.y = __fadd_rn(acc[i][j + 1], bias[bn + col0 + j + 1]);
            v.z = __fadd_rn(acc[i][j + 2], bias[bn + col0 + j + 2]);
            v.w = __fadd_rn(acc[i][j + 3], bias[bn + col0 + j + 3]);
            *reinterpret_cast<float4*>(&C[r * GN + bn + col0 + j]) = v;
        }
    }
}

// ---------------- Phase 2: sequential LIF scan ----------------
// One thread per (b,h). I_in layout [B, T, H]; per-t wave read = 64
// consecutive floats (256 B, coalesced). Unroll-16 keeps 16 independent
// loads in flight to cover HBM latency at 1 wave/CU occupancy.
__global__ __launch_bounds__(64) void lif_scan_kernel(
    const float* __restrict__ I,   // [B, T, H]
    float* __restrict__ O)         // [B, T, H]
{
    const int idx = blockIdx.x * 64 + threadIdx.x;   // 0..16383
    const int b = idx >> 9;          // / HIDDEN
    const int h = idx & 511;

    const size_t base = (size_t)b * TIME * HIDDEN + h;
    const float* Ip = I + base;
    float*       Op = O + base;

    // exp(-DT/TAU_MEM)=exp(-0.05), exp(-DT/TAU_SYN)=exp(-0.2),
    // rounded-to-nearest fp32 (matches np.exp on fp32 input)
    const float am = 0.95122942450071400910f;
    const float as = 0.81873075307798185867f;

    float v = 0.0f, s = 0.0f;

    #pragma unroll 1
    for (int t = 0; t < TIME; t += 16) {
        float buf[16];
        #pragma unroll
        for (int u = 0; u < 16; ++u)
            buf[u] = Ip[(size_t)(t + u) * HIDDEN];

        float ob[16];
        #pragma unroll
        for (int u = 0; u < 16; ++u) {
            // separate mul/add roundings to match numpy (no FMA contraction)
            s = __fadd_rn(__fmul_rn(as, s), buf[u]);
            v = __fadd_rn(__fmul_rn(am, v), s);
            const float o = (v > 1.0f) ? 1.0f : 0.0f;
            v = __fsub_rn(v, o);
            ob[u] = o;
        }

        #pragma unroll
        for (int u = 0; u < 16; ++u)
            Op[(size_t)(t + u) * HIDDEN] = ob[u];
    }
}

extern "C" void kernel_launch(void* const* d_in, const int* in_sizes, int n_in,
                              void* d_out, int out_size, void* d_ws, size_t ws_size,
                              hipStream_t stream) {
    const float* spikes = (const float*)d_in[0];   // [32, 1024, 512]
    const float* W      = (const float*)d_in[1];   // [512, 512]
    const float* bias   = (const float*)d_in[2];   // [512]
    float* out  = (float*)d_out;                   // [32, 1024, 512]
    float* I_in = (float*)d_ws;                    // 64 MiB scratch

    dim3 g1(GN / BN, GM / BM);                     // (4, 256)
    sgemm_bias_kernel<<<g1, 256, 0, stream>>>(spikes, W, bias, I_in);

    lif_scan_kernel<<<BATCH * HIDDEN / 64, 64, 0, stream>>>(I_in, out);
}